// Round 1
// baseline (298.857 us; speedup 1.0000x reference)
//
#include <hip/hip_runtime.h>
#include <math.h>

#define NTHREADS 256

namespace {
constexpr int D   = 128;   // feature dim
constexpr int G   = 32;    // gaussians
constexpr int H   = 8;     // heads
constexpr int HD  = 16;    // head dim
constexpr int KNB = 48;    // neighbors
constexpr int KP1 = 49;    // neighbors + self
constexpr int NN  = 512;   // atoms per batch entry

// kv row stride padded: 132 % 32 = 4 -> 8 distinct t's in a wave hit 8
// distinct bank groups in the score phase (128 would be 8-way conflict).
constexpr int KV_STRIDE = 132;
constexpr int F_STRIDE  = 52;
constexpr int SC_STRIDE = 52;

constexpr float LOG_LO = -2.302585092994046f;  // ln(0.1)
constexpr float LOG_HI =  1.609437912434100f;  // ln(5.0)
constexpr float GWIDTH = (LOG_HI - LOG_LO) / 31.0f;
constexpr float GCOEFF = -0.5f / (GWIDTH * GWIDTH);
constexpr float PI_OVER_CUT = 3.14159265358979323846f / 5.0f;
}  // namespace

__global__ __launch_bounds__(NTHREADS) void tdt_kernel(
    const float* __restrict__ positions,  // (B,N,3)
    const int*   __restrict__ z,          // (B,N)
    const int*   __restrict__ neighbors,  // (B,N,K)
    const float* __restrict__ nmask,      // (B,N,K)
    const float* __restrict__ embedding,  // (100,D)
    const float* __restrict__ filt_W,     // (G,D)
    const float* __restrict__ filt_b,     // (D)
    const float* __restrict__ Wq,         // (D,D)
    const float* __restrict__ Wk,
    const float* __restrict__ Wv,
    const float* __restrict__ Wo,
    float* __restrict__ out)              // (B,N,D)
{
  __shared__ float s_fT[G * F_STRIDE];     // gauss features, [g][t]
  __shared__ float s_kv[KP1 * KV_STRIDE];  // kv_in, [t][d] padded
  __shared__ float s_x[D];                 // center embedding
  __shared__ float s_q[D];                 // q projection
  __shared__ float s_qk[D * H];            // Wk-folded q, [d][h]
  __shared__ float s_p[H * D];             // attn-weighted kv, [h][d]
  __shared__ float s_sc[H * SC_STRIDE];    // scores / attn, [h][t]
  __shared__ float s_agg[D];
  __shared__ float s_lr[KP1];              // log(r)
  __shared__ float s_C[KP1];               // cosine cutoff
  __shared__ float s_mask[KP1];
  __shared__ int   s_zj[KP1];              // neighbor species

  const int a   = blockIdx.x;       // global atom index = b*NN + n
  const int b   = a >> 9;           // NN = 512
  const int n   = a & (NN - 1);
  const int tid = threadIdx.x;

  // ---- P0: center embedding ----
  if (tid < D) s_x[tid] = embedding[z[a] * D + tid];

  // ---- P1: geometry (distances, cutoff, neighbor species) ----
  if (tid < KP1) {
    int j; float m;
    if (tid == 0) { j = n; m = 1.0f; }
    else {
      j = neighbors[a * KNB + tid - 1];
      m = nmask[a * KNB + tid - 1];
    }
    float r;
    if (tid == 0) {
      r = 0.01f;
    } else {
      const float dx = positions[(b * NN + j) * 3 + 0] - positions[a * 3 + 0];
      const float dy = positions[(b * NN + j) * 3 + 1] - positions[a * 3 + 1];
      const float dz = positions[(b * NN + j) * 3 + 2] - positions[a * 3 + 2];
      r = sqrtf(dx * dx + dy * dy + dz * dz + 1e-12f);
    }
    s_lr[tid]   = __logf(r);
    s_C[tid]    = (r < 5.0f) ? (0.5f * (__cosf(r * PI_OVER_CUT) + 1.0f)) : 0.0f;
    s_mask[tid] = m;
    s_zj[tid]   = z[b * NN + j];
  }
  __syncthreads();

  // ---- P2: log-normal smearing features, stored transposed [g][t] ----
  for (int i = tid; i < KP1 * G; i += NTHREADS) {
    const int t = i >> 5;          // G = 32
    const int g = i & 31;
    const float dlt = s_lr[t] - (LOG_LO + (float)g * GWIDTH);
    s_fT[g * F_STRIDE + t] = __expf(GCOEFF * dlt * dlt);
  }
  __syncthreads();

  // ---- P3: filter network + kv_in = x_j * W * C ----
  // Register-accumulator form: each filt_W element read once per half-block.
  {
    const int d    = tid & (D - 1);
    const int half = tid >> 7;           // 0: t in [0,24); 1: t in [24,49)
    const int t0   = half ? 24 : 0;
    float acc[25];
    const float bv = filt_b[d];
#pragma unroll
    for (int tt = 0; tt < 25; ++tt) acc[tt] = bv;
    for (int g = 0; g < G; ++g) {
      const float fw = filt_W[g * D + d];
      const float* fr = &s_fT[g * F_STRIDE + t0];
#pragma unroll
      for (int tt = 0; tt < 25; ++tt) acc[tt] = fmaf(fr[tt], fw, acc[tt]);
    }
    if (half) {
#pragma unroll
      for (int tt = 0; tt < 25; ++tt) {
        const int t = 24 + tt;
        s_kv[t * KV_STRIDE + d] =
            embedding[s_zj[t] * D + d] * (acc[tt] * s_C[t]);
      }
    } else {
#pragma unroll
      for (int tt = 0; tt < 24; ++tt) {  // acc[24] discarded (owned by half 1)
        s_kv[tt * KV_STRIDE + d] =
            embedding[s_zj[tt] * D + d] * (acc[tt] * s_C[tt]);
      }
    }
  }
  __syncthreads();

  // ---- P4: q = x @ Wq ----
  if (tid < D) {
    const int d = tid;
    float acc = 0.0f;
    for (int e = 0; e < D; ++e) acc = fmaf(s_x[e], Wq[e * D + d], acc);
    s_q[d] = acc;
  }
  __syncthreads();

  // ---- P5: fold Wk into q:  qk[d][h] = sum_e Wk[d][h*16+e] * q[h*16+e] ----
  {
    const int d  = tid & (D - 1);
    const int h0 = tid >> 7;             // 0 or 1
#pragma unroll
    for (int hh = 0; hh < 4; ++hh) {
      const int h = h0 * 4 + hh;
      float acc = 0.0f;
#pragma unroll
      for (int e = 0; e < HD; ++e)
        acc = fmaf(Wk[d * D + h * HD + e], s_q[h * HD + e], acc);
      s_qk[d * H + h] = acc;
    }
  }
  __syncthreads();

  // ---- P6: scores[h][t] = (kv_t . qk_h) / 4, masked ----
  for (int i = tid; i < KP1 * H; i += NTHREADS) {
    const int t = i >> 3;
    const int h = i & 7;
    float acc = 0.0f;
    for (int d = 0; d < D; ++d)
      acc = fmaf(s_kv[t * KV_STRIDE + d], s_qk[d * H + h], acc);
    float sc = acc * 0.25f;              // 1/sqrt(hd=16)
    if (s_mask[t] <= 0.0f) sc = -1e9f;
    s_sc[h * SC_STRIDE + t] = sc;
  }
  __syncthreads();

  // ---- P7: per-head softmax over 49 slots ----
  if (tid < H) {
    float* row = &s_sc[tid * SC_STRIDE];
    float m = -1e30f;
    for (int t = 0; t < KP1; ++t) m = fmaxf(m, row[t]);
    float s = 0.0f;
    for (int t = 0; t < KP1; ++t) {
      const float e = __expf(row[t] - m);
      row[t] = e;
      s += e;
    }
    const float inv = 1.0f / s;
    for (int t = 0; t < KP1; ++t) row[t] *= inv;
  }
  __syncthreads();

  // ---- P8: p[h][d] = sum_t attn[h][t] * kv[t][d] ----
  {
    const int d  = tid & (D - 1);
    const int h0 = tid >> 7;             // handles heads h0*4 .. h0*4+3
    float a0 = 0.0f, a1 = 0.0f, a2 = 0.0f, a3 = 0.0f;
    for (int t = 0; t < KP1; ++t) {
      const float kvv = s_kv[t * KV_STRIDE + d];
      a0 = fmaf(s_sc[(h0 * 4 + 0) * SC_STRIDE + t], kvv, a0);
      a1 = fmaf(s_sc[(h0 * 4 + 1) * SC_STRIDE + t], kvv, a1);
      a2 = fmaf(s_sc[(h0 * 4 + 2) * SC_STRIDE + t], kvv, a2);
      a3 = fmaf(s_sc[(h0 * 4 + 3) * SC_STRIDE + t], kvv, a3);
    }
    s_p[(h0 * 4 + 0) * D + d] = a0;
    s_p[(h0 * 4 + 1) * D + d] = a1;
    s_p[(h0 * 4 + 2) * D + d] = a2;
    s_p[(h0 * 4 + 3) * D + d] = a3;
  }
  __syncthreads();

  // ---- P9: agg[c] = sum_d p[h(c)][d] * Wv[d][c] ----
  if (tid < D) {
    const int c = tid;
    const int h = c >> 4;                // hd = 16
    float acc = 0.0f;
    for (int d = 0; d < D; ++d)
      acc = fmaf(s_p[h * D + d], Wv[d * D + c], acc);
    s_agg[c] = acc;
  }
  __syncthreads();

  // ---- P10: out = x + agg @ Wo ----
  if (tid < D) {
    const int c = tid;
    float acc = s_x[c];
    for (int e = 0; e < D; ++e)
      acc = fmaf(s_agg[e], Wo[e * D + c], acc);
    out[a * D + c] = acc;
  }
}

extern "C" void kernel_launch(void* const* d_in, const int* in_sizes, int n_in,
                              void* d_out, int out_size, void* d_ws, size_t ws_size,
                              hipStream_t stream) {
  const float* positions = (const float*)d_in[0];
  const int*   z         = (const int*)d_in[1];
  const int*   neighbors = (const int*)d_in[2];
  const float* nmask     = (const float*)d_in[3];
  const float* embedding = (const float*)d_in[4];
  const float* filt_W    = (const float*)d_in[5];
  const float* filt_b    = (const float*)d_in[6];
  const float* Wq        = (const float*)d_in[7];
  const float* Wk        = (const float*)d_in[8];
  const float* Wv        = (const float*)d_in[9];
  const float* Wo        = (const float*)d_in[10];
  float* out = (float*)d_out;

  const int natoms = in_sizes[1];  // B*N = 16*512 = 8192
  tdt_kernel<<<natoms, NTHREADS, 0, stream>>>(
      positions, z, neighbors, nmask, embedding, filt_W, filt_b,
      Wq, Wk, Wv, Wo, out);
}